// Round 7
// baseline (2595.863 us; speedup 1.0000x reference)
//
#include <hip/hip_runtime.h>
#include <math.h>

#define H 256
#define G3 768        // 3*H
#define BB 512
#define AA 4
#define EE 10
#define RP (BB*AA*EE) // 20480 physical rows
#define RA (BB*AA)    // 2048 action rows
#define TT 10
#define NMV 2
#define STEPSC 0.05f
#define NBLK 256      // blocks; 2 batches per block
#define PRB 80        // phys rows per block
#define DST 260       // LDS D stride in floats (2-way bank aliasing = free)

typedef __attribute__((ext_vector_type(8))) short short8;
typedef __attribute__((ext_vector_type(8))) _Float16 half8;
typedef __attribute__((ext_vector_type(4))) float f32x4;

#if defined(__has_builtin)
#  if __has_builtin(__builtin_amdgcn_global_load_lds)
#    define HAS_GLL 1
#  endif
#endif

__device__ __forceinline__ float sigmoid_(float x){ return 1.f/(1.f + __expf(-x)); }
__device__ __forceinline__ float tanh_(float x){
    float ax = fabsf(x);
    float e  = __expf(-2.f*ax);
    float t  = (1.f - e)/(1.f + e);
    return copysignf(t, x);
}
__device__ __forceinline__ float elu_(float x){ return x > 0.f ? x : (__expf(x) - 1.f); }

#define MFMA16(A,B,C) __builtin_amdgcn_mfma_f32_16x16x32_f16(A,B,C,0,0,0)

// monotone float<->uint encoding for atomicMax-based pooling (all real encs > 0)
__device__ __forceinline__ unsigned int enc_(float f){
    unsigned int u = __float_as_uint(f);
    return (u & 0x80000000u) ? ~u : (u | 0x80000000u);
}
__device__ __forceinline__ float dec_(unsigned int e){
    unsigned int u = (e & 0x80000000u) ? (e & 0x7fffffffu) : ~e;
    return __uint_as_float(u);
}

// 16B/lane global->LDS copy (async direct-to-LDS when available)
__device__ __forceinline__ void cp16(const void* g, void* l) {
#ifdef HAS_GLL
    __builtin_amdgcn_global_load_lds(
        (const __attribute__((address_space(1))) unsigned int*)g,
        (__attribute__((address_space(3))) unsigned int*)l, 16, 0, 0);
#else
    *(short8*)l = *(const short8*)g;
#endif
}

// split 8 consecutive fp32 into fp16 hi + fp16 lo fragments (global or LDS ptr)
__device__ __forceinline__ void split8(const float* p, half8& hi, half8& lo) {
    float4 v0 = *(const float4*)p;
    float4 v1 = *(const float4*)(p + 4);
    float f[8] = {v0.x, v0.y, v0.z, v0.w, v1.x, v1.y, v1.z, v1.w};
    #pragma unroll
    for (int e = 0; e < 8; e++) {
        _Float16 h = (_Float16)f[e];
        hi[e] = h;
        lo[e] = (_Float16)(f[e] - (float)h);
    }
}

// ---------------------------------------------------------------------------
// fp32 weight [Nout][ldsrc] -> fp16 in MFMA B-fragment order.
// i = ((chunk*8 + kc)*64 + lane)*8 + j ; row = chunk*16+(lane&15),
// k = kc*32 + (lane>>4)*8 + j.  Chunk = 16 output cols x 256 k = 4096 halfs.
// ---------------------------------------------------------------------------
__global__ void k_splitw(const float* __restrict__ src, _Float16* __restrict__ dst,
                         int n, int ldsrc)
{
    int i = blockIdx.x*256 + threadIdx.x;
    if (i < n) {
        int j  = i & 7;
        int l  = (i >> 3) & 63;
        int kc = (i >> 9) & 7;
        int c  = i >> 12;
        int row = c*16 + (l & 15);
        int k   = kc*32 + (l >> 4)*8 + j;
        dst[i] = (_Float16)src[(size_t)row*ldsrc + k];
    }
}

// gia[ra][k] = b_ih_a[k] + sum_{j<3} goals[ra][j]*W_ih_a[k][256+j]
__global__ void k_gia_goal(const float* __restrict__ goals,
                           const float* __restrict__ Wiha,
                           const float* __restrict__ biha,
                           float* __restrict__ out)
{
    int idx = blockIdx.x*256 + threadIdx.x;
    int ra = idx / G3, k = idx % G3;
    float g0 = goals[ra*3+0], g1 = goals[ra*3+1], g2 = goals[ra*3+2];
    const float* w = Wiha + (size_t)k*259 + 256;
    out[idx] = biha[k] + g0*w[0] + g1*w[1] + g2*w[2];
}

// ha padded init: [blk][16][H]; rows 0-7 = mema rows (blk*8+r), rows 8-15 = 0
__global__ void k_init_ha(const float* __restrict__ mema, float* __restrict__ ha)
{
    int i = blockIdx.x*256 + threadIdx.x;   // NBLK*16*H
    int blk = i / (16*H);
    int rem = i % (16*H);
    int r = rem / H, c = rem % H;
    ha[i] = (r < 8) ? mema[((size_t)blk*8 + r)*H + c] : 0.f;
}

// GRU epilogue helper (phys): inline input gates (K=5) + gate math -> hp in place
__device__ __forceinline__ void gru_epi(const f32x4 acc[3], int rowq /*row0+quad*4*/,
                                        const float xvv[4][5], int col, float* hp,
                                        const float* Wih, const float* bih,
                                        const float* bhh)
{
    const float br = bih[col], bz = bih[256+col], bn = bih[512+col];
    const float cr = bhh[col], cz = bhh[256+col], cn = bhh[512+col];
    const float* wr = Wih + (size_t)col*5;
    const float* wz = Wih + (size_t)(256+col)*5;
    const float* wn = Wih + (size_t)(512+col)*5;
    #pragma unroll
    for (int r = 0; r < 4; r++) {
        int row = rowq + r;
        float gr = br, gz = bz, gn = bn;
        #pragma unroll
        for (int j = 0; j < 5; j++) {
            gr = fmaf(xvv[r][j], wr[j], gr);
            gz = fmaf(xvv[r][j], wz[j], gz);
            gn = fmaf(xvv[r][j], wn[j], gn);
        }
        float hr = acc[0][r] + cr;
        float hz = acc[1][r] + cz;
        float hn = acc[2][r] + cn;
        float rg = sigmoid_(gr + hr);
        float z  = sigmoid_(gz + hz);
        float n  = tanh_(gn + rg*hn);
        size_t idx = (size_t)row*H + col;
        hp[idx] = (1.f - z)*n + z*hp[idx];
    }
}

// ---------------------------------------------------------------------------
// MEGA KERNEL: all 10 steps, both chains. Block = 2 batches (80 phys rows,
// 8 action rows). 256 blocks x 256 thr (4 waves). Phys: 5 tiles, waves own
// tile wv + 1/4 of tile 4 (slice-partitioned). Weights: fp16 frag-order,
// GRU/FC staged via dbuf global_load_lds; action read direct from L2.
// Pool: fc epilogue -> LDS atomicMax (monotone-uint). States in-place global.
// ---------------------------------------------------------------------------
__global__ __launch_bounds__(256, 1)
void k_mega(float* hp, float* ha,
            const _Float16* __restrict__ wWhh, const _Float16* __restrict__ wWfc,
            const _Float16* __restrict__ wWhha, const _Float16* __restrict__ wWiha,
            const _Float16* __restrict__ wWfca, const _Float16* __restrict__ wWm1,
            const float* __restrict__ gia,
            const float* __restrict__ obs, const float* __restrict__ phys,
            const float* __restrict__ Wih, const float* __restrict__ bih,
            const float* __restrict__ bhh, const float* __restrict__ bfcp,
            const float* __restrict__ bhha, const float* __restrict__ bfca,
            const float* __restrict__ bm1,
            const float* __restrict__ Wm2, const float* __restrict__ bm2,
            float* __restrict__ out)
{
    __shared__ _Float16 WB[2][12288];   // 48 KB weight dbuf
    __shared__ float D[8*DST];          // 8.3 KB feat/proca/m1o (+pool accum)
    unsigned int* Du = (unsigned int*)D;

    const int tid = threadIdx.x;
    const int wv = tid >> 6, lane = tid & 63;
    const int quad = lane >> 4, l16 = lane & 15;
    const int blk = blockIdx.x;

    const int prow0 = blk*PRB;
    const int myrow = prow0 + wv*16;    // own tile base
    const int t4row = prow0 + 64;       // shared tile base

    // time-invariant epilogue inputs (own tile + shared tile rows)
    float xv[4][5], xv4[4][5];
    #pragma unroll
    for (int r = 0; r < 4; r++) {
        int rb = myrow + quad*4 + r;
        xv[r][0] = obs[(size_t)rb*2+0]; xv[r][1] = obs[(size_t)rb*2+1];
        int b = rb/(AA*EE), e = rb%EE;
        const float* pp = phys + (size_t)(b*EE+e)*3;
        xv[r][2]=pp[0]; xv[r][3]=pp[1]; xv[r][4]=pp[2];
        rb = t4row + quad*4 + r;
        xv4[r][0]=obs[(size_t)rb*2+0]; xv4[r][1]=obs[(size_t)rb*2+1];
        b = rb/(AA*EE); e = rb%EE;
        const float* p4 = phys + (size_t)(b*EE+e)*3;
        xv4[r][2]=p4[0]; xv4[r][3]=p4[1]; xv4[r][4]=p4[2];
    }

    auto stage_gru = [&](int cs, int buf) {
        #pragma unroll
        for (int k = 0; k < 6; k++) {
            int i = tid + 256*k;
            int g = i >> 9, off = (i & 511)*8;
            cp16(wWhh + (size_t)(g*16+cs)*4096 + off, &WB[buf][g*4096 + off]);
        }
    };
    auto stage_fc = [&](int cs, int buf) {
        #pragma unroll
        for (int k = 0; k < 2; k++) {
            int i = tid + 256*k;
            cp16(wWfc + (size_t)cs*4096 + i*8, &WB[buf][i*8]);
        }
    };

    stage_gru(0, 0);

    for (int t = 0; t < TT; t++) {
        // ================= PHYS GRU =================
        half8 Ahi[8], Alo[8], Bh4[8], Bl4[8];
        {
            const float* ar = hp + (size_t)(myrow + l16)*H + quad*8;
            const float* a4 = hp + (size_t)(t4row + l16)*H + quad*8;
            #pragma unroll
            for (int kc = 0; kc < 8; kc++) {
                split8(ar + kc*32, Ahi[kc], Alo[kc]);
                split8(a4 + kc*32, Bh4[kc], Bl4[kc]);
            }
        }
        for (int cs = 0; cs < 16; cs++) {
            __syncthreads();                       // WB[cs&1] staged
            if (cs < 15) stage_gru(cs+1, (cs+1)&1);
            else         stage_fc(0, 0);
            const _Float16* wb = WB[cs&1];
            const bool own4 = ((cs>>2) == wv);
            f32x4 acc[3], acc4[3];
            #pragma unroll
            for (int g = 0; g < 3; g++) {
                acc[g]  = (f32x4){0.f,0.f,0.f,0.f};
                acc4[g] = (f32x4){0.f,0.f,0.f,0.f};
            }
            #pragma unroll
            for (int kc = 0; kc < 8; kc++) {
                #pragma unroll
                for (int g = 0; g < 3; g++) {
                    half8 b = *(const half8*)&wb[(g*8+kc)*512 + lane*8];
                    acc[g] = MFMA16(Ahi[kc], b, acc[g]);
                    acc[g] = MFMA16(Alo[kc], b, acc[g]);
                    if (own4) {
                        acc4[g] = MFMA16(Bh4[kc], b, acc4[g]);
                        acc4[g] = MFMA16(Bl4[kc], b, acc4[g]);
                    }
                }
            }
            const int col = cs*16 + l16;
            gru_epi(acc, myrow + quad*4, xv, col, hp, Wih, bih, bhh);
            if (own4) gru_epi(acc4, t4row + quad*4, xv4, col, hp, Wih, bih, bhh);
        }
        __threadfence_block();
        // init pool accum
        for (int i = tid; i < 8*DST; i += 256) Du[i] = 0u;
        __syncthreads();   // (A) h' visible, accum init done, fc(0) staged

        // ================= FC + POOL =================
        {
            const float* ar = hp + (size_t)(myrow + l16)*H + quad*8;
            const float* a4 = hp + (size_t)(t4row + l16)*H + quad*8;
            #pragma unroll
            for (int kc = 0; kc < 8; kc++) {
                split8(ar + kc*32, Ahi[kc], Alo[kc]);
                split8(a4 + kc*32, Bh4[kc], Bl4[kc]);
            }
        }
        for (int cs = 0; cs < 16; cs++) {
            if (cs) __syncthreads();
            if (cs < 15) stage_fc(cs+1, (cs+1)&1);
            const _Float16* wb = WB[cs&1];
            const bool own4 = ((cs>>2) == wv);
            f32x4 acc = (f32x4){0.f,0.f,0.f,0.f};
            f32x4 acc4 = (f32x4){0.f,0.f,0.f,0.f};
            #pragma unroll
            for (int kc = 0; kc < 8; kc++) {
                half8 b = *(const half8*)&wb[kc*512 + lane*8];
                acc = MFMA16(Ahi[kc], b, acc);
                acc = MFMA16(Alo[kc], b, acc);
                if (own4) { acc4 = MFMA16(Bh4[kc], b, acc4); acc4 = MFMA16(Bl4[kc], b, acc4); }
            }
            const int col = cs*16 + l16;
            const float bs = bfcp[col];
            #pragma unroll
            for (int r = 0; r < 4; r++) {
                int rb = wv*16 + quad*4 + r;
                atomicMax(&Du[(rb/10)*DST + col], enc_(elu_(acc[r] + bs)));
            }
            if (own4) {
                #pragma unroll
                for (int r = 0; r < 4; r++) {
                    int rb = 64 + quad*4 + r;
                    atomicMax(&Du[(rb/10)*DST + col], enc_(elu_(acc4[r] + bs)));
                }
            }
        }
        __syncthreads();   // (B) pool atomics done
        for (int i = tid; i < 8*H; i += 256) {
            int r = i >> 8, c = i & 255;
            D[r*DST + c] = dec_(Du[r*DST + c]);
        }
        __syncthreads();   // (C) feat ready
        if (t < TT-1) stage_gru(0, 0);   // overlap next GRU staging with action

        // ================= ACTION =================
        half8 Fhi[8], Flo[8], Hhi[8], Hlo[8];
        #pragma unroll
        for (int kc = 0; kc < 8; kc++) {
            if (l16 < 8) split8(&D[l16*DST + quad*8 + kc*32], Fhi[kc], Flo[kc]);
            else {
                #pragma unroll
                for (int j = 0; j < 8; j++) { Fhi[kc][j] = (_Float16)0; Flo[kc][j] = (_Float16)0; }
            }
            split8(ha + (size_t)(blk*16 + l16)*H + quad*8 + kc*32, Hhi[kc], Hlo[kc]);
        }
        // action GRU (gh and gi GEMMs fused), 2 passes of 2 col-chunks
        #pragma unroll
        for (int p = 0; p < 2; p++) {
            f32x4 gh[3][2], gx[3][2];
            #pragma unroll
            for (int g = 0; g < 3; g++)
                #pragma unroll
                for (int ch = 0; ch < 2; ch++) {
                    gh[g][ch] = (f32x4){0.f,0.f,0.f,0.f};
                    gx[g][ch] = (f32x4){0.f,0.f,0.f,0.f};
                }
            #pragma unroll
            for (int kc = 0; kc < 8; kc++)
                #pragma unroll
                for (int ch = 0; ch < 2; ch++)
                    #pragma unroll
                    for (int g = 0; g < 3; g++) {
                        const size_t cg = (size_t)(g*16 + wv*4 + p*2 + ch);
                        half8 bh = *(const half8*)(wWhha + (cg*8+kc)*512 + lane*8);
                        half8 bx = *(const half8*)(wWiha + (cg*8+kc)*512 + lane*8);
                        gh[g][ch] = MFMA16(Hhi[kc], bh, gh[g][ch]);
                        gh[g][ch] = MFMA16(Hlo[kc], bh, gh[g][ch]);
                        gx[g][ch] = MFMA16(Fhi[kc], bx, gx[g][ch]);
                        gx[g][ch] = MFMA16(Flo[kc], bx, gx[g][ch]);
                    }
            if (quad < 2) {
                #pragma unroll
                for (int ch = 0; ch < 2; ch++) {
                    const int c = wv*64 + (p*2+ch)*16 + l16;
                    const float br = bhha[c], bz = bhha[256+c], bn = bhha[512+c];
                    #pragma unroll
                    for (int r = 0; r < 4; r++) {
                        int ar = quad*4 + r;   // 0..7
                        const float* gp = gia + (size_t)(blk*8 + ar)*G3;
                        float rg = sigmoid_(gp[c]     + gx[0][ch][r] + gh[0][ch][r] + br);
                        float z  = sigmoid_(gp[256+c] + gx[1][ch][r] + gh[1][ch][r] + bz);
                        float n  = tanh_(gp[512+c] + gx[2][ch][r] + rg*(gh[2][ch][r] + bn));
                        size_t idx = (size_t)(blk*16 + ar)*H + c;
                        ha[idx] = (1.f - z)*n + z*ha[idx];
                    }
                }
            }
        }
        __threadfence_block();
        __syncthreads();   // (D) h_a' visible

        // fc_a: proca = elu(h_a' @ Wfca^T + bfca) -> D
        #pragma unroll
        for (int kc = 0; kc < 8; kc++)
            split8(ha + (size_t)(blk*16 + l16)*H + quad*8 + kc*32, Hhi[kc], Hlo[kc]);
        {
            f32x4 ac[4];
            #pragma unroll
            for (int ch = 0; ch < 4; ch++) ac[ch] = (f32x4){0.f,0.f,0.f,0.f};
            #pragma unroll
            for (int kc = 0; kc < 8; kc++)
                #pragma unroll
                for (int ch = 0; ch < 4; ch++) {
                    half8 b = *(const half8*)(wWfca + ((size_t)(wv*4+ch)*8+kc)*512 + lane*8);
                    ac[ch] = MFMA16(Hhi[kc], b, ac[ch]);
                    ac[ch] = MFMA16(Hlo[kc], b, ac[ch]);
                }
            if (quad < 2) {
                #pragma unroll
                for (int ch = 0; ch < 4; ch++) {
                    const int c = wv*64 + ch*16 + l16;
                    const float bs = bfca[c];
                    #pragma unroll
                    for (int r = 0; r < 4; r++)
                        D[(quad*4+r)*DST + c] = elu_(ac[ch][r] + bs);
                }
            }
        }
        __syncthreads();   // (E) proca in D

        // m1: m1o = elu(proca @ Wm1^T + bm1) -> D (after all frag reads)
        #pragma unroll
        for (int kc = 0; kc < 8; kc++) {
            if (l16 < 8) split8(&D[l16*DST + quad*8 + kc*32], Fhi[kc], Flo[kc]);
            else {
                #pragma unroll
                for (int j = 0; j < 8; j++) { Fhi[kc][j] = (_Float16)0; Flo[kc][j] = (_Float16)0; }
            }
        }
        __syncthreads();   // (F) frag reads done before D overwrite
        {
            f32x4 ac[4];
            #pragma unroll
            for (int ch = 0; ch < 4; ch++) ac[ch] = (f32x4){0.f,0.f,0.f,0.f};
            #pragma unroll
            for (int kc = 0; kc < 8; kc++)
                #pragma unroll
                for (int ch = 0; ch < 4; ch++) {
                    half8 b = *(const half8*)(wWm1 + ((size_t)(wv*4+ch)*8+kc)*512 + lane*8);
                    ac[ch] = MFMA16(Fhi[kc], b, ac[ch]);
                    ac[ch] = MFMA16(Flo[kc], b, ac[ch]);
                }
            if (quad < 2) {
                #pragma unroll
                for (int ch = 0; ch < 4; ch++) {
                    const int c = wv*64 + ch*16 + l16;
                    const float bs = bm1[c];
                    #pragma unroll
                    for (int r = 0; r < 4; r++)
                        D[(quad*4+r)*DST + c] = elu_(ac[ch][r] + bs);
                }
            }
        }
        __syncthreads();   // (G) m1o ready

        // m2: mv = tanh(m1o @ Wm2^T + bm2) * STEP
        if (tid < 16) {
            int r = tid >> 1, v = tid & 1;
            const float* w = Wm2 + (size_t)v*H;
            float s = bm2[v];
            #pragma unroll 4
            for (int i = 0; i < H/4; i++) {
                float4 a = *(const float4*)&D[r*DST + i*4];
                float4 b = *(const float4*)&w[i*4];
                s = fmaf(a.x,b.x,s); s = fmaf(a.y,b.y,s);
                s = fmaf(a.z,b.z,s); s = fmaf(a.w,b.w,s);
            }
            out[((size_t)t*RA + blk*8 + r)*NMV + v] = tanh_(s)*STEPSC;
        }
        // next iteration's first __syncthreads protects D/m2 and WB reuse
    }
}

extern "C" void kernel_launch(void* const* d_in, const int* in_sizes, int n_in,
                              void* d_out, int out_size, void* d_ws, size_t ws_size,
                              hipStream_t stream)
{
    const float* obs  = (const float*)d_in[0];
    const float* phys = (const float*)d_in[1];
    const float* goals= (const float*)d_in[2];
    const float* memp = (const float*)d_in[3];
    const float* mema = (const float*)d_in[4];
    const float* Wihp = (const float*)d_in[5];
    const float* Whhp = (const float*)d_in[6];
    const float* bihp = (const float*)d_in[7];
    const float* bhhp = (const float*)d_in[8];
    const float* Wfcp = (const float*)d_in[9];
    const float* bfcp = (const float*)d_in[10];
    const float* Wiha = (const float*)d_in[11];
    const float* Whha = (const float*)d_in[12];
    const float* biha = (const float*)d_in[13];
    const float* bhha = (const float*)d_in[14];
    const float* Wfca = (const float*)d_in[15];
    const float* bfca = (const float*)d_in[16];
    const float* Wm1  = (const float*)d_in[17];
    const float* bm1  = (const float*)d_in[18];
    const float* Wm2  = (const float*)d_in[19];
    const float* bm2  = (const float*)d_in[20];
    float* out = (float*)d_out;
    (void)ws_size;

    char* base = (char*)d_ws;
    size_t off = 0;
    auto alloc = [&](size_t bytes) -> char* {
        char* p = base + off;
        off += (bytes + 255) & ~(size_t)255;
        return p;
    };
    _Float16* wp_whh = (_Float16*)alloc((size_t)G3*H*2);
    _Float16* wp_wfc = (_Float16*)alloc((size_t)H*H*2);
    _Float16* wa_whh = (_Float16*)alloc((size_t)G3*H*2);
    _Float16* wa_wih = (_Float16*)alloc((size_t)G3*H*2);
    _Float16* wa_wfc = (_Float16*)alloc((size_t)H*H*2);
    _Float16* wa_wm1 = (_Float16*)alloc((size_t)H*H*2);
    float* gia = (float*)alloc((size_t)RA*G3*4);
    float* hp  = (float*)alloc((size_t)RP*H*4);
    float* ha  = (float*)alloc((size_t)NBLK*16*H*4);

    // --- pre-pass ---
    k_splitw<<<(G3*H+255)/256, 256, 0, stream>>>(Whhp, wp_whh, G3*H, H);
    k_splitw<<<(H*H+255)/256, 256, 0, stream>>>(Wfcp, wp_wfc, H*H, H);
    k_splitw<<<(G3*H+255)/256, 256, 0, stream>>>(Whha, wa_whh, G3*H, H);
    k_splitw<<<(G3*H+255)/256, 256, 0, stream>>>(Wiha, wa_wih, G3*H, 259);
    k_splitw<<<(H*H+255)/256, 256, 0, stream>>>(Wfca, wa_wfc, H*H, H);
    k_splitw<<<(H*H+255)/256, 256, 0, stream>>>(Wm1,  wa_wm1, H*H, H);
    k_gia_goal<<<RA*G3/256, 256, 0, stream>>>(goals, Wiha, biha, gia);
    k_init_ha<<<NBLK*16*H/256, 256, 0, stream>>>(mema, ha);
    hipMemcpyAsync(hp, memp, sizeof(float)*(size_t)RP*H, hipMemcpyDeviceToDevice, stream);

    // --- the whole model in one launch ---
    k_mega<<<NBLK, 256, 0, stream>>>(hp, ha,
                                     wp_whh, wp_wfc, wa_whh, wa_wih, wa_wfc, wa_wm1,
                                     gia, obs, phys,
                                     Wihp, bihp, bhhp, bfcp,
                                     bhha, bfca, bm1, Wm2, bm2, out);
}

// Round 8
// 797.963 us; speedup vs baseline: 3.2531x; 3.2531x over previous
//
#include <hip/hip_runtime.h>
#include <math.h>

#define H 256
#define G3 768        // 3*H
#define BB 512
#define AA 4
#define EE 10
#define RP (BB*AA*EE) // 20480 physical rows
#define RA (BB*AA)    // 2048 action rows
#define TT 10
#define NMV 2
#define STEPSC 0.05f
#define DST 260       // act LDS row stride (floats)
#define ACTB 128      // action blocks (scheduled first)
#define GRUB 1280     // gru blocks (320 x 4)
#define FCB  1280     // fc blocks  (320 x 4)

typedef __attribute__((ext_vector_type(8))) short short8;
typedef __attribute__((ext_vector_type(8))) _Float16 half8;
typedef __attribute__((ext_vector_type(4))) float f32x4;

#if defined(__has_builtin)
#  if __has_builtin(__builtin_amdgcn_global_load_lds)
#    define HAS_GLL 1
#  endif
#endif

__device__ __forceinline__ float sigmoid_(float x){ return 1.f/(1.f + __expf(-x)); }
__device__ __forceinline__ float tanh_(float x){
    float ax = fabsf(x);
    float e  = __expf(-2.f*ax);
    float t  = (1.f - e)/(1.f + e);
    return copysignf(t, x);
}
__device__ __forceinline__ float elu_(float x){ return x > 0.f ? x : (__expf(x) - 1.f); }

#define MFMA16(A,B,C) __builtin_amdgcn_mfma_f32_16x16x32_f16(A,B,C,0,0,0)

__device__ __forceinline__ void cp16(const void* g, void* l) {
#ifdef HAS_GLL
    __builtin_amdgcn_global_load_lds(
        (const __attribute__((address_space(1))) unsigned int*)g,
        (__attribute__((address_space(3))) unsigned int*)l, 16, 0, 0);
#else
    *(short8*)l = *(const short8*)g;
#endif
}

// ---------------------------------------------------------------------------
// fp32 weight [Nout][ldsrc] -> fp16 in MFMA B-fragment order.
// i = ((chunk*8 + kc)*64 + lane)*8 + j ; row = chunk*16+(lane&15),
// k = kc*32 + (lane>>4)*8 + j.  Chunk = 16 output cols x 256 k = 4096 halfs.
// ---------------------------------------------------------------------------
__global__ void k_splitw(const float* __restrict__ src, _Float16* __restrict__ dst,
                         int n, int ldsrc)
{
    int i = blockIdx.x*256 + threadIdx.x;
    if (i < n) {
        int j  = i & 7;
        int l  = (i >> 3) & 63;
        int kc = (i >> 9) & 7;
        int c  = i >> 12;
        int row = c*16 + (l & 15);
        int k   = kc*32 + (l >> 4)*8 + j;
        dst[i] = (_Float16)src[(size_t)row*ldsrc + k];
    }
}

// gia[ra][k] = b_ih_a[k] + sum_{j<3} goals[ra][j]*W_ih_a[k][256+j]
__global__ void k_gia_goal(const float* __restrict__ goals,
                           const float* __restrict__ Wiha,
                           const float* __restrict__ biha,
                           float* __restrict__ out)
{
    int idx = blockIdx.x*256 + threadIdx.x;
    int ra = idx / G3, k = idx % G3;
    float g0 = goals[ra*3+0], g1 = goals[ra*3+1], g2 = goals[ra*3+2];
    const float* w = Wiha + (size_t)k*259 + 256;
    out[idx] = biha[k] + g0*w[0] + g1*w[1] + g2*w[2];
}

// fp32 -> fp16 convert (state init)
__global__ void k_cvt(const float* __restrict__ src, _Float16* __restrict__ dst, int n)
{
    int i = blockIdx.x*256 + threadIdx.x;
    if (i < n) dst[i] = (_Float16)src[i];
}

// ---------------------------------------------------------------------------
// FUSED STEP KERNEL. Launch L has three independent roles:
//   blocks [0,ACTB):            action chain for step act_t  (pool..m2)
//   blocks [ACTB,ACTB+GRUB):    physical GRU for step gru_t
//   blocks [ACTB+GRUB, +FCB):   fc_p for step fc_t
// States fp16; single-term fp16 MFMA; weights fp16 frag-order.
// hp ping-pong: gru(t) reads hp[t&1] writes hp[1-(t&1)]; fc(t) reads hp[(t+1)&1].
// proc ping-pong: fc(t) writes proc[t&1]; act(t) reads proc[t&1]. ha in-place.
// ---------------------------------------------------------------------------
__global__ __launch_bounds__(256, 2)
void k_step(int gru_t, int fc_t, int act_t,
            _Float16* __restrict__ hp0, _Float16* __restrict__ hp1,
            _Float16* __restrict__ proc0, _Float16* __restrict__ proc1,
            _Float16* __restrict__ ha,
            const _Float16* __restrict__ wWhh, const _Float16* __restrict__ wWfc,
            const _Float16* __restrict__ wWhha, const _Float16* __restrict__ wWiha,
            const _Float16* __restrict__ wWfca, const _Float16* __restrict__ wWm1,
            const float* __restrict__ gia,
            const float* __restrict__ obs, const float* __restrict__ phys,
            const float* __restrict__ Wih, const float* __restrict__ bih,
            const float* __restrict__ bhh, const float* __restrict__ bfcp,
            const float* __restrict__ bhha, const float* __restrict__ bfca,
            const float* __restrict__ bm1,
            const float* __restrict__ Wm2, const float* __restrict__ bm2,
            float* __restrict__ out)
{
    __shared__ char smem[24576];
    int b = blockIdx.x;
    const int tid = threadIdx.x;
    const int wv = tid >> 6, lane = tid & 63;
    const int quad = lane >> 4, l16 = lane & 15;

    // ===================== ACTION ROLE =====================
    if (b < ACTB) {
        if (act_t < 0) return;
        float* D = (float*)smem;
        const _Float16* proc = (act_t & 1) ? proc1 : proc0;
        const int ra0 = b*16;

        // pool: feat = max_e proc
        for (int i = tid; i < 16*256; i += 256) {
            int r = i >> 8, c = i & 255;
            const _Float16* p = proc + ((size_t)(ra0 + r)*EE)*H + c;
            float m = (float)p[0];
            #pragma unroll
            for (int e = 1; e < EE; e++) m = fmaxf(m, (float)p[(size_t)e*H]);
            D[r*DST + c] = m;
        }
        __syncthreads();

        half8 Fh[8], Hh[8];
        #pragma unroll
        for (int kc = 0; kc < 8; kc++) {
            const float* fp = &D[l16*DST + quad*8 + kc*32];
            #pragma unroll
            for (int j = 0; j < 8; j++) Fh[kc][j] = (_Float16)fp[j];
            Hh[kc] = *(const half8*)(ha + (size_t)(ra0 + l16)*H + quad*8 + kc*32);
        }

        // action GRU (gh and gi GEMMs fused), 2 passes x 2 col-chunks per wave
        #pragma unroll
        for (int p = 0; p < 2; p++) {
            f32x4 gh[3][2], gx[3][2];
            #pragma unroll
            for (int g = 0; g < 3; g++)
                #pragma unroll
                for (int ch = 0; ch < 2; ch++) {
                    gh[g][ch] = (f32x4){0.f,0.f,0.f,0.f};
                    gx[g][ch] = (f32x4){0.f,0.f,0.f,0.f};
                }
            #pragma unroll
            for (int kc = 0; kc < 8; kc++)
                #pragma unroll
                for (int ch = 0; ch < 2; ch++)
                    #pragma unroll
                    for (int g = 0; g < 3; g++) {
                        const size_t cg = (size_t)(g*16 + wv*4 + p*2 + ch);
                        half8 bh = *(const half8*)(wWhha + (cg*8+kc)*512 + lane*8);
                        half8 bx = *(const half8*)(wWiha + (cg*8+kc)*512 + lane*8);
                        gh[g][ch] = MFMA16(Hh[kc], bh, gh[g][ch]);
                        gx[g][ch] = MFMA16(Fh[kc], bx, gx[g][ch]);
                    }
            #pragma unroll
            for (int ch = 0; ch < 2; ch++) {
                const int c = wv*64 + (p*2+ch)*16 + l16;
                const float br = bhha[c], bz = bhha[256+c], bn = bhha[512+c];
                #pragma unroll
                for (int reg = 0; reg < 4; reg++) {
                    const int r = quad*4 + reg;
                    const float* gp = gia + (size_t)(ra0 + r)*G3;
                    float rg = sigmoid_(gp[c]     + gx[0][ch][reg] + gh[0][ch][reg] + br);
                    float z  = sigmoid_(gp[256+c] + gx[1][ch][reg] + gh[1][ch][reg] + bz);
                    float n  = tanh_(gp[512+c] + gx[2][ch][reg] + rg*(gh[2][ch][reg] + bn));
                    size_t idx = (size_t)(ra0 + r)*H + c;
                    float hprev = (float)ha[idx];
                    ha[idx] = (_Float16)((1.f - z)*n + z*hprev);
                }
            }
        }
        __threadfence_block();
        __syncthreads();   // h_a' visible; feat reads done -> D reusable

        // fc_a: proca = elu(h_a' @ Wfca^T + bfca) -> D
        #pragma unroll
        for (int kc = 0; kc < 8; kc++)
            Hh[kc] = *(const half8*)(ha + (size_t)(ra0 + l16)*H + quad*8 + kc*32);
        {
            f32x4 ac[4];
            #pragma unroll
            for (int ch = 0; ch < 4; ch++) ac[ch] = (f32x4){0.f,0.f,0.f,0.f};
            #pragma unroll
            for (int kc = 0; kc < 8; kc++)
                #pragma unroll
                for (int ch = 0; ch < 4; ch++) {
                    half8 w = *(const half8*)(wWfca + ((size_t)(wv*4+ch)*8+kc)*512 + lane*8);
                    ac[ch] = MFMA16(Hh[kc], w, ac[ch]);
                }
            #pragma unroll
            for (int ch = 0; ch < 4; ch++) {
                const int c = wv*64 + ch*16 + l16;
                const float bs = bfca[c];
                #pragma unroll
                for (int reg = 0; reg < 4; reg++)
                    D[(quad*4+reg)*DST + c] = elu_(ac[ch][reg] + bs);
            }
        }
        __syncthreads();   // proca ready

        // m1: m1o = elu(proca @ Wm1^T + bm1) -> D
        #pragma unroll
        for (int kc = 0; kc < 8; kc++) {
            const float* fp = &D[l16*DST + quad*8 + kc*32];
            #pragma unroll
            for (int j = 0; j < 8; j++) Fh[kc][j] = (_Float16)fp[j];
        }
        __syncthreads();   // reads done before overwrite
        {
            f32x4 ac[4];
            #pragma unroll
            for (int ch = 0; ch < 4; ch++) ac[ch] = (f32x4){0.f,0.f,0.f,0.f};
            #pragma unroll
            for (int kc = 0; kc < 8; kc++)
                #pragma unroll
                for (int ch = 0; ch < 4; ch++) {
                    half8 w = *(const half8*)(wWm1 + ((size_t)(wv*4+ch)*8+kc)*512 + lane*8);
                    ac[ch] = MFMA16(Fh[kc], w, ac[ch]);
                }
            #pragma unroll
            for (int ch = 0; ch < 4; ch++) {
                const int c = wv*64 + ch*16 + l16;
                const float bs = bm1[c];
                #pragma unroll
                for (int reg = 0; reg < 4; reg++)
                    D[(quad*4+reg)*DST + c] = elu_(ac[ch][reg] + bs);
            }
        }
        __syncthreads();   // m1o ready

        // m2
        if (tid < 32) {
            int r = tid >> 1, v = tid & 1;
            const float* w = Wm2 + (size_t)v*H;
            float s = bm2[v];
            #pragma unroll 4
            for (int i = 0; i < H/4; i++) {
                float4 a = *(const float4*)&D[r*DST + i*4];
                float4 c = *(const float4*)&w[i*4];
                s = fmaf(a.x,c.x,s); s = fmaf(a.y,c.y,s);
                s = fmaf(a.z,c.z,s); s = fmaf(a.w,c.w,s);
            }
            out[((size_t)act_t*RA + ra0 + r)*NMV + v] = tanh_(s)*STEPSC;
        }
        return;
    }
    b -= ACTB;

    // ===================== PHYS GRU ROLE =====================
    if (b < GRUB) {
        if (gru_t < 0) return;
        _Float16* Bw = (_Float16*)smem;
        const _Float16* hin  = (gru_t & 1) ? hp1 : hp0;
        _Float16*       hout = (gru_t & 1) ? hp0 : hp1;
        const int xm = b % 320, ys = b / 320;
        const int m0 = xm*64 + wv*16;

        half8 Ah[8];
        #pragma unroll
        for (int kc = 0; kc < 8; kc++)
            Ah[kc] = *(const half8*)(hin + (size_t)(m0 + l16)*H + quad*8 + kc*32);

        float xv[4][5];
        #pragma unroll
        for (int r = 0; r < 4; r++) {
            int row = m0 + quad*4 + r;
            xv[r][0] = obs[(size_t)row*2+0];
            xv[r][1] = obs[(size_t)row*2+1];
            int bb = row / (AA*EE), e = row % EE;
            const float* pp = phys + (size_t)(bb*EE + e)*3;
            xv[r][2]=pp[0]; xv[r][3]=pp[1]; xv[r][4]=pp[2];
        }

        for (int s = 0; s < 4; s++) {
            const int cs = ys*4 + s;
            if (s) __syncthreads();
            #pragma unroll
            for (int k = 0; k < 6; k++) {
                int i = tid + 256*k;
                int g = i >> 9;
                cp16(wWhh + (size_t)(g*16+cs)*4096 + (i & 511)*8, &Bw[(size_t)i*8]);
            }
            __syncthreads();

            f32x4 acc[3];
            #pragma unroll
            for (int g = 0; g < 3; g++) acc[g] = (f32x4){0.f,0.f,0.f,0.f};
            #pragma unroll
            for (int kc = 0; kc < 8; kc++)
                #pragma unroll
                for (int g = 0; g < 3; g++) {
                    half8 w = *(const half8*)&Bw[(g*8 + kc)*512 + lane*8];
                    acc[g] = MFMA16(Ah[kc], w, acc[g]);
                }

            const int col = cs*16 + l16;
            const float bhr = bhh[col], bhz = bhh[256+col], bhn = bhh[512+col];
            const float br_ = bih[col], bz_ = bih[256+col], bn_ = bih[512+col];
            float wr[5], wz[5], wn[5];
            {
                const float* pr = Wih + (size_t)col*5;
                const float* pz = Wih + (size_t)(256+col)*5;
                const float* pn = Wih + (size_t)(512+col)*5;
                #pragma unroll
                for (int j = 0; j < 5; j++) { wr[j]=pr[j]; wz[j]=pz[j]; wn[j]=pn[j]; }
            }
            #pragma unroll
            for (int r = 0; r < 4; r++) {
                int row = m0 + quad*4 + r;
                float gr = br_, gz = bz_, gn = bn_;
                #pragma unroll
                for (int j = 0; j < 5; j++) {
                    gr = fmaf(xv[r][j], wr[j], gr);
                    gz = fmaf(xv[r][j], wz[j], gz);
                    gn = fmaf(xv[r][j], wn[j], gn);
                }
                float rg = sigmoid_(gr + acc[0][r] + bhr);
                float z  = sigmoid_(gz + acc[1][r] + bhz);
                float n  = tanh_(gn + rg*(acc[2][r] + bhn));
                size_t idx = (size_t)row*H + col;
                float hprev = (float)hin[idx];
                hout[idx] = (_Float16)((1.f - z)*n + z*hprev);
            }
        }
        return;
    }
    b -= GRUB;

    // ===================== FC ROLE =====================
    {
        if (fc_t < 0) return;
        _Float16* Bw = (_Float16*)smem;
        const _Float16* xin = ((fc_t+1) & 1) ? hp1 : hp0;
        _Float16*      pout = (fc_t & 1) ? proc1 : proc0;
        const int xm = b % 320, ys = b / 320;
        const int m0 = xm*64 + wv*16;

        half8 Ah[8];
        #pragma unroll
        for (int kc = 0; kc < 8; kc++)
            Ah[kc] = *(const half8*)(xin + (size_t)(m0 + l16)*H + quad*8 + kc*32);

        for (int s = 0; s < 2; s++) {
            const int cs = ys*2 + s;   // 0..7, 32 cols each
            if (s) __syncthreads();
            #pragma unroll
            for (int k = 0; k < 4; k++) {
                int i = tid + 256*k;
                cp16(wWfc + (size_t)cs*8192 + i*8, &Bw[(size_t)i*8]);
            }
            __syncthreads();

            f32x4 acc[2];
            acc[0] = (f32x4){0.f,0.f,0.f,0.f};
            acc[1] = (f32x4){0.f,0.f,0.f,0.f};
            #pragma unroll
            for (int kc = 0; kc < 8; kc++)
                #pragma unroll
                for (int ni = 0; ni < 2; ni++) {
                    half8 w = *(const half8*)&Bw[ni*4096 + kc*512 + lane*8];
                    acc[ni] = MFMA16(Ah[kc], w, acc[ni]);
                }
            #pragma unroll
            for (int ni = 0; ni < 2; ni++) {
                const int col = cs*32 + ni*16 + l16;
                const float bs = bfcp[col];
                #pragma unroll
                for (int r = 0; r < 4; r++) {
                    int row = m0 + quad*4 + r;
                    pout[(size_t)row*H + col] = (_Float16)elu_(acc[ni][r] + bs);
                }
            }
        }
    }
}

extern "C" void kernel_launch(void* const* d_in, const int* in_sizes, int n_in,
                              void* d_out, int out_size, void* d_ws, size_t ws_size,
                              hipStream_t stream)
{
    const float* obs  = (const float*)d_in[0];
    const float* phys = (const float*)d_in[1];
    const float* goals= (const float*)d_in[2];
    const float* memp = (const float*)d_in[3];
    const float* mema = (const float*)d_in[4];
    const float* Wihp = (const float*)d_in[5];
    const float* Whhp = (const float*)d_in[6];
    const float* bihp = (const float*)d_in[7];
    const float* bhhp = (const float*)d_in[8];
    const float* Wfcp = (const float*)d_in[9];
    const float* bfcp = (const float*)d_in[10];
    const float* Wiha = (const float*)d_in[11];
    const float* Whha = (const float*)d_in[12];
    const float* biha = (const float*)d_in[13];
    const float* bhha = (const float*)d_in[14];
    const float* Wfca = (const float*)d_in[15];
    const float* bfca = (const float*)d_in[16];
    const float* Wm1  = (const float*)d_in[17];
    const float* bm1  = (const float*)d_in[18];
    const float* Wm2  = (const float*)d_in[19];
    const float* bm2  = (const float*)d_in[20];
    float* out = (float*)d_out;
    (void)ws_size;

    char* base = (char*)d_ws;
    size_t off = 0;
    auto alloc = [&](size_t bytes) -> char* {
        char* p = base + off;
        off += (bytes + 255) & ~(size_t)255;
        return p;
    };
    _Float16* wp_whh = (_Float16*)alloc((size_t)G3*H*2);
    _Float16* wp_wfc = (_Float16*)alloc((size_t)H*H*2);
    _Float16* wa_whh = (_Float16*)alloc((size_t)G3*H*2);
    _Float16* wa_wih = (_Float16*)alloc((size_t)G3*H*2);
    _Float16* wa_wfc = (_Float16*)alloc((size_t)H*H*2);
    _Float16* wa_wm1 = (_Float16*)alloc((size_t)H*H*2);
    float*    gia    = (float*)alloc((size_t)RA*G3*4);
    _Float16* hp0    = (_Float16*)alloc((size_t)RP*H*2);
    _Float16* hp1    = (_Float16*)alloc((size_t)RP*H*2);
    _Float16* proc0  = (_Float16*)alloc((size_t)RP*H*2);
    _Float16* proc1  = (_Float16*)alloc((size_t)RP*H*2);
    _Float16* ha     = (_Float16*)alloc((size_t)RA*H*2);

    // --- pre-pass ---
    k_splitw<<<(G3*H+255)/256, 256, 0, stream>>>(Whhp, wp_whh, G3*H, H);
    k_splitw<<<(H*H+255)/256, 256, 0, stream>>>(Wfcp, wp_wfc, H*H, H);
    k_splitw<<<(G3*H+255)/256, 256, 0, stream>>>(Whha, wa_whh, G3*H, H);
    k_splitw<<<(G3*H+255)/256, 256, 0, stream>>>(Wiha, wa_wih, G3*H, 259);
    k_splitw<<<(H*H+255)/256, 256, 0, stream>>>(Wfca, wa_wfc, H*H, H);
    k_splitw<<<(H*H+255)/256, 256, 0, stream>>>(Wm1,  wa_wm1, H*H, H);
    k_gia_goal<<<RA*G3/256, 256, 0, stream>>>(goals, Wiha, biha, gia);
    k_cvt<<<((size_t)RP*H+255)/256, 256, 0, stream>>>(memp, hp0, RP*H);
    k_cvt<<<((size_t)RA*H+255)/256, 256, 0, stream>>>(mema, ha, RA*H);

    // --- 12 fused-step launches: L has gru(L), fc(L-1), act(L-2) ---
    const int NB = ACTB + GRUB + FCB;
    for (int L = 0; L <= TT + 1; L++) {
        int gru_t = (L <= TT-1) ? L : -1;
        int fc_t  = (L-1 >= 0 && L-1 <= TT-1) ? L-1 : -1;
        int act_t = (L-2 >= 0) ? L-2 : -1;
        k_step<<<NB, 256, 0, stream>>>(gru_t, fc_t, act_t,
                                       hp0, hp1, proc0, proc1, ha,
                                       wp_whh, wp_wfc, wa_whh, wa_wih, wa_wfc, wa_wm1,
                                       gia, obs, phys,
                                       Wihp, bihp, bhhp, bfcp,
                                       bhha, bfca, bm1, Wm2, bm2, out);
    }
}